// Round 11
// baseline (285.049 us; speedup 1.0000x reference)
//
#include <hip/hip_runtime.h>
#include <hip/hip_bf16.h>

// GAT encoder: B=16, N=768, IN=16, HID=64, HEADS=8, EMB=128, 2 GAT layers.
// Round 11: sort-scan attention. P~ = max(e1*e2, f1*f2); sorting m by t2 makes
// each row's branches a suffix/prefix -> prefix-sum scans replace the N^2
// PV MFMA. Phase A (Wh via MFMA + u-MFMA s1/s2, fragment LDS) is unchanged
// from verified rounds 8-10. hp is now ROW-MAJOR bf16 (coalesced emission);
// consumers (phase A A-loads, k_projm) read row-major.
//
// ws: h0r us[786432] | hp0 us[6291456] | hp1 us[6291456] | W1f us[262144]
//     | pwf us[65536] | W0f us[32768] | u1F us[65536] | u0F us[8192]

#define B_ 16
#define N_ 768
#define IN_DIM_ 16
#define HID_ 64
#define EMB_ 128
#define NH_ 8
#define LOG2E_ 1.4426950408889634f

typedef __attribute__((ext_vector_type(4))) float f32x4;
typedef __attribute__((ext_vector_type(8))) short bf16x8;
typedef __attribute__((ext_vector_type(4))) short bf16x4;
typedef unsigned long long u64;

typedef __attribute__((address_space(1))) const unsigned int gu32;
typedef __attribute__((address_space(3))) unsigned int lu32;

static __device__ __forceinline__ void gload_lds16(const void* g, void* l) {
    __builtin_amdgcn_global_load_lds((gu32*)g, (lu32*)l, 16, 0, 0);
}
static __device__ __forceinline__ short f2bf(float x) {
    __hip_bfloat16 b = __float2bfloat16(x);
    return *reinterpret_cast<short*>(&b);
}
static __device__ __forceinline__ float bf2f(ushort u) {
    unsigned int v = ((unsigned int)u) << 16;
    union { unsigned int i; float f; } c; c.i = v; return c.f;
}
// monotone float->uint encode (order-preserving for all finite floats)
static __device__ __forceinline__ unsigned int fenc(float f) {
    union { float f; unsigned int i; } c; c.f = f;
    unsigned int u = c.i;
    return (u & 0x80000000u) ? ~u : (u | 0x80000000u);
}

// block-wide bitonic ascending sort of a[0..SZ), SZ power of 2, any thread count
static __device__ void bitonic(u64* a, int SZ, int tid, int nthr) {
    for (int k = 2; k <= SZ; k <<= 1) {
        for (int j = k >> 1; j > 0; j >>= 1) {
            __syncthreads();
            for (int t = tid; t < (SZ >> 1); t += nthr) {
                int i = ((t & ~(j - 1)) << 1) | (t & (j - 1));
                int l = i | j;
                bool up = ((i & k) == 0);
                u64 x = a[i], y = a[l];
                bool sw = up ? (x > y) : (x < y);
                if (sw) { a[i] = y; a[l] = x; }
            }
        }
    }
    __syncthreads();
}

// ---- prep: h0 ROW-MAJOR bf16 + W1f/pwf/W0f B-frags + u1F/u0F (verified parts) ----
__global__ __launch_bounds__(256) void k_prep(const float* __restrict__ x,
                                              const float* __restrict__ ipw,
                                              const float* __restrict__ ipb,
                                              const float* __restrict__ w1,
                                              const float* __restrict__ pw,
                                              const float* __restrict__ w0,
                                              const float* __restrict__ a1g,
                                              const float* __restrict__ a0g,
                                              ushort* __restrict__ h0r,
                                              ushort* __restrict__ W1f,
                                              ushort* __restrict__ pwf,
                                              ushort* __restrict__ W0f,
                                              ushort* __restrict__ u1F,
                                              ushort* __restrict__ u0F) {
    const int bid = blockIdx.x;
    const int tid = threadIdx.x;
    if (bid < 384) {
        const int t = bid * 256 + tid;   // < 98304
        const int row = t >> 3;          // 0..12287
        const int o0 = (t & 7) * 8;
        const float* xr = x + row * IN_DIM_;
        float xv[IN_DIM_];
#pragma unroll
        for (int f = 0; f < IN_DIM_; ++f) xv[f] = xr[f];
        bf16x8 v;
#pragma unroll
        for (int j = 0; j < 8; ++j) {
            float acc = ipb[o0 + j];
#pragma unroll
            for (int f = 0; f < IN_DIM_; ++f) acc = fmaf(xv[f], ipw[f * HID_ + o0 + j], acc);
            v[j] = f2bf(acc);
        }
        *(bf16x8*)&h0r[(size_t)row * 64 + o0] = v;
        return;
    }
    if (bid < 560) {
        int t = (bid - 384) * 256 + tid;  // < 45056
        if (t < 32768) {
            int lane = t & 63, nt = (t >> 6) & 3, kt = (t >> 8) & 15, h = t >> 12;
            int k0 = kt * 32 + (lane >> 4) * 8;
            int col = nt * 16 + (lane & 15);
            const float* src = w1 + (h * 512 + k0) * 64 + col;
            bf16x8 v;
#pragma unroll
            for (int j = 0; j < 8; ++j) v[j] = f2bf(src[j * 64]);
            *(bf16x8*)&W1f[t * 8] = v;
        } else if (t < 40960) {
            int u = t - 32768;
            int lane = u & 63, nt = (u >> 6) & 7, kt = u >> 9;
            int k0 = kt * 32 + (lane >> 4) * 8;
            int col = nt * 16 + (lane & 15);
            const float* src = pw + k0 * 128 + col;
            bf16x8 v;
#pragma unroll
            for (int j = 0; j < 8; ++j) v[j] = f2bf(src[j * 128]);
            *(bf16x8*)&pwf[u * 8] = v;
        } else {
            int u = t - 40960;
            int lane = u & 63, nt = (u >> 6) & 3, kt = (u >> 8) & 1, h = u >> 9;
            int k0 = kt * 32 + (lane >> 4) * 8;
            int col = nt * 16 + (lane & 15);
            const float* src = w0 + (h * 64 + k0) * 64 + col;
            bf16x8 v;
#pragma unroll
            for (int j = 0; j < 8; ++j) v[j] = f2bf(src[j * 64]);
            *(bf16x8*)&W0f[u * 8] = v;
        }
        return;
    }
    // u-fragment blocks (verified round 9/10)
    int ub = bid - 560;  // < 144
    const float* W;
    const float* A;
    ushort* dst;
    if (ub < 128) {
        int h = ub >> 4, kt = ub & 15;
        W = w1 + (h * 512 + kt * 32) * 64;
        A = a1g + h * 128;
        dst = u1F + (h * 16 + kt) * 512;
    } else {
        int v2 = ub - 128;
        int h = v2 >> 1, kt = v2 & 1;
        W = w0 + (h * 64 + kt * 32) * 64;
        A = a0g + h * 128;
        dst = u0F + (h * 2 + kt) * 512;
    }
    ((unsigned int*)dst)[tid] = 0u;
    __syncthreads();
    const int sel = tid >> 7, kl = (tid >> 2) & 31, og4 = tid & 3;
    const float* Wr = W + kl * 64 + og4 * 16;
    const float* Ar = A + sel * 64 + og4 * 16;
    float r = 0.f;
#pragma unroll
    for (int q = 0; q < 4; ++q) {
        float4 wv = *(const float4*)&Wr[q * 4];
        float4 av = *(const float4*)&Ar[q * 4];
        r += wv.x * av.x + wv.y * av.y + wv.z * av.z + wv.w * av.w;
    }
    r += __shfl_xor(r, 1);
    r += __shfl_xor(r, 2);
    if (og4 == 0)
        dst[((kl >> 3) * 16 + sel) * 8 + (kl & 7)] = (ushort)f2bf(r * LOG2E_);
}

// ---- fused GAT layer: block (b,h,half) -> Wh(MFMA) -> sort-scan attention ----
template <int KT>
__global__ __launch_bounds__(768, 3) void k_gat(const ushort* __restrict__ Arow,
                                                const ushort* __restrict__ Bfrag,
                                                const ushort* __restrict__ uF,
                                                ushort* __restrict__ hpO) {
    constexpr int KW = KT * 32;   // A row width (features)
    __shared__ __align__(16) ushort whf[49152];   // 96KB Wh fragments (aliases W1f stage)
    __shared__ __align__(16) float s1s[N_], s2s[N_];
    __shared__ __align__(16) u64 sbuf[1024];      // sort buffer (t2, then row keys)
    __shared__ __align__(16) float ts[N_], es[N_], fs[N_], ep[N_], fp[N_];
    __shared__ __align__(16) float e1a[384], f1a[384], ivd[384];
    __shared__ __align__(16) float CE[12 * 64], CF[12 * 64];
    __shared__ __align__(16) float wte[12], wtf[12];
    __shared__ __align__(16) ushort prm[N_];

    const int bid = blockIdx.x;
    const int b = bid & 15;          // same-b blocks share an XCD
    const int hh = bid >> 4;
    const int h = hh >> 1;
    const int half = hh & 1;

    const int tid = threadIdx.x;
    const int lane = tid & 63;
    const int w = tid >> 6;          // 0..11
    const int lg = lane >> 4;
    const int ll = lane & 15;

    // ================= Phase A: Wh(768x64) + s1/s2 (verified) =================
    if constexpr (KT == 16) {
        const ushort* src = Bfrag + h * 16 * 2048;   // 64KB W1f[h], 1KB wave-chunks
        for (int c = w; c < 64; c += 12)
            gload_lds16(src + c * 512 + lane * 8, (char*)whf + c * 1024);
        __syncthreads();
    }

    f32x4 acc[4][4];
    f32x4 accs[4];
#pragma unroll
    for (int i = 0; i < 4; ++i) {
        accs[i] = (f32x4){0.f, 0.f, 0.f, 0.f};
#pragma unroll
        for (int nt = 0; nt < 4; ++nt) acc[i][nt] = (f32x4){0.f, 0.f, 0.f, 0.f};
    }

    const ushort* Ab = Arow + (size_t)(b * 768) * KW;
    auto loadA4 = [&](bf16x8* dst, int kt) {
#pragma unroll
        for (int i = 0; i < 4; ++i)
            dst[i] = *(const bf16x8*)&Ab[(size_t)(w * 64 + i * 16 + ll) * KW + kt * 32 + lg * 8];
    };
    auto loadB4 = [&](bf16x8* dst, int kt) {
        if constexpr (KT == 16) {
#pragma unroll
            for (int nt = 0; nt < 4; ++nt)
                dst[nt] = *(const bf16x8*)&whf[kt * 2048 + nt * 512 + lane * 8];
        } else {
#pragma unroll
            for (int nt = 0; nt < 4; ++nt)
                dst[nt] = *(const bf16x8*)&Bfrag[((h * 2 + kt) * 4 + nt) * 512 + lane * 8];
        }
    };
    auto stepA = [&](const bf16x8* afr, const bf16x8* bfr, bf16x8 ufr) {
#pragma unroll
        for (int i = 0; i < 4; ++i) {
#pragma unroll
            for (int nt = 0; nt < 4; ++nt)
                acc[i][nt] = __builtin_amdgcn_mfma_f32_16x16x32_bf16(afr[i], bfr[nt], acc[i][nt], 0, 0, 0);
            accs[i] = __builtin_amdgcn_mfma_f32_16x16x32_bf16(afr[i], ufr, accs[i], 0, 0, 0);
        }
    };

    {
        bf16x8 aA[4], aB[4];
        loadA4(aA, 0);
        for (int kt = 0; kt < KT; kt += 2) {
            loadA4(aB, kt + 1);
            bf16x8 bfr[4];
            loadB4(bfr, kt);
            bf16x8 ufr = *(const bf16x8*)&uF[(h * KT + kt) * 512 + lane * 8];
            stepA(aA, bfr, ufr);
            if (kt + 2 < KT) loadA4(aA, kt + 2);
            loadB4(bfr, kt + 1);
            ufr = *(const bf16x8*)&uF[(h * KT + kt + 1) * 512 + lane * 8];
            stepA(aB, bfr, ufr);
        }
    }
    if constexpr (KT == 16) __syncthreads();  // staged-B reads done before overwrite

    // Wh fragments -> LDS (j-packed b64, verified), s1/s2 (t-domain) -> LDS
#pragma unroll
    for (int i = 0; i < 4; ++i) {
        const int rt = w * 4 + i;
        const int lp = ((rt * 2 + (lg >> 1)) & 3) * 16 + ll;
        const int j0 = 4 * (lg & 1);
#pragma unroll
        for (int nt = 0; nt < 4; ++nt) {
            bf16x4 pk;
#pragma unroll
            for (int reg = 0; reg < 4; ++reg) pk[reg] = f2bf(acc[i][nt][reg]);
            *(bf16x4*)&whf[(((rt >> 1) * 4 + nt) * 64 + lp) * 8 + j0] = pk;
        }
#pragma unroll
        for (int reg = 0; reg < 4; ++reg) {
            const int row = rt * 16 + lg * 4 + reg;
            if (ll == 0) s1s[row] = accs[i][reg];
            else if (ll == 1) s2s[row] = accs[i][reg];
        }
    }
    __syncthreads();

    // ================= sort t2 (keys ascending, perm in low word) =================
    for (int i = tid; i < 1024; i += 768)
        sbuf[i] = (i < N_) ? ((((u64)fenc(s2s[i])) << 32) | (u64)i) : ~0ull;
    bitonic(sbuf, 1024, tid, 768);

    // derive perm / sorted t2 / factors
    if (tid < N_) {
        int m = (int)(unsigned int)sbuf[tid];
        prm[tid] = (ushort)m;
        float t = s2s[m];
        ts[tid] = t;
        es[tid] = exp2f(t);
        fs[tid] = exp2f(0.2f * t);
    }
    __syncthreads();

    // scalar exclusive prefixes ep/fp (wave w handles [w*64, w*64+64))
    {
        float ve = es[w * 64 + lane];
        float vf = fs[w * 64 + lane];
        float ie = ve, jf = vf;
        for (int off = 1; off < 64; off <<= 1) {
            float ue = __shfl_up(ie, off);
            float uf = __shfl_up(jf, off);
            if (lane >= off) { ie += ue; jf += uf; }
        }
        if (lane == 63) { wte[w] = ie; wtf[w] = jf; }
        float eloc = ie - ve, floc = jf - vf;
        __syncthreads();
        float oe = 0.f, of2 = 0.f;
        for (int ww = 0; ww < w; ++ww) { oe += wte[ww]; of2 += wtf[ww]; }
        ep[w * 64 + lane] = eloc + oe;
        fp[w * 64 + lane] = floc + of2;
    }
    __syncthreads();

    // per-row: e1/f1, k(n) via binary search, denominator
    int myk = 0;
    if (tid < 384) {
        const int ng = half * 384 + tid;
        const float t1 = s1s[ng];
        const float e1 = exp2f(t1);
        const float f1 = exp2f(0.2f * t1);
        const float v = -t1;
        int lo = 0, hi = N_;
        while (lo < hi) { int mid = (lo + hi) >> 1; if (ts[mid] < v) lo = mid + 1; else hi = mid; }
        myk = lo;
        const float etot = ep[N_ - 1] + es[N_ - 1];
        const float ftot = fp[N_ - 1] + fs[N_ - 1];
        const float epk = (myk < N_) ? ep[myk] : etot;
        const float fpk = (myk < N_) ? fp[myk] : ftot;
        const float d = e1 * (etot - epk) + f1 * fpk;
        e1a[tid] = e1; f1a[tid] = f1; ivd[tid] = 1.0f / d;
    }
    __syncthreads();

    // sort rows by k: key = (k<<9)|n  (k<=768 -> 10 bits, n<384 -> 9 bits)
    if (tid < 512)
        sbuf[tid] = (tid < 384) ? (u64)(((unsigned int)myk << 9) | (unsigned int)tid) : ~0ull;
    bitonic(sbuf, 512, tid, 768);

    // chunk vector scans: wave c totals over its 64 sorted m's
    const int c = w;
    auto whval = [&](int m) {
        return bf2f(whf[(m >> 5) * 2048 + (lane >> 4) * 512 +
                        (((m >> 3) & 3) * 16 + (lane & 15)) * 8 + (m & 7)]);
    };
    {
        float SE = 0.f, SF = 0.f;
        for (int i = 0; i < 64; ++i) {
            const int gi = c * 64 + i;
            const float whv = whval(prm[gi]);
            SE = fmaf(es[gi], whv, SE);
            SF = fmaf(fs[gi], whv, SF);
        }
        CE[c * 64 + lane] = SE;
        CF[c * 64 + lane] = SF;
    }
    __syncthreads();

    float PE = 0.f, PF = 0.f, Etot = 0.f;
    for (int cc = 0; cc < 12; ++cc) {
        const float ve = CE[cc * 64 + lane];
        Etot += ve;
        if (cc < c) { PE += ve; PF += CF[cc * 64 + lane]; }
    }

    // emission bounds for this wave (rows with k in [c*64, (c+1)*64); c=11 also k=768)
    auto LB512 = [&](u64 t) {
        int lo = 0, hi = 512;
        while (lo < hi) { int mid = (lo + hi) >> 1; if (sbuf[mid] < t) lo = mid + 1; else hi = mid; }
        return lo;
    };
    const int loB = LB512(((u64)(c * 64)) << 9);
    const int hiB = (c == 11) ? LB512(((u64)769) << 9) : LB512(((u64)((c + 1) * 64)) << 9);

    // merge-emission: re-scan chunk, emit rows at their k position
    const size_t rowG0 = (size_t)(b * 768 + half * 384);
    ushort* outb = hpO + (size_t)h * 64 + lane;
    int ptr = loB;
    float SEl = 0.f, SFl = 0.f;
    for (int i = 0; i < 64; ++i) {
        const unsigned int target = (unsigned int)(c * 64 + i);
        while (ptr < hiB) {
            const u64 key = sbuf[ptr];
            if ((unsigned int)(key >> 9) != target) break;
            const int n = (int)(key & 511u);
            const float val = (e1a[n] * (Etot - (PE + SEl)) + f1a[n] * (PF + SFl)) * ivd[n];
            outb[(rowG0 + n) * 512] = (ushort)f2bf(val);
            ++ptr;
        }
        const int gi = c * 64 + i;
        const float whv = whval(prm[gi]);
        SEl = fmaf(es[gi], whv, SEl);
        SFl = fmaf(fs[gi], whv, SFl);
    }
    while (ptr < hiB) {   // k == 768 rows (all-F), only reachable for c == 11
        const u64 key = sbuf[ptr];
        const int n = (int)(key & 511u);
        const float val = (e1a[n] * (Etot - (PE + SEl)) + f1a[n] * (PF + SFl)) * ivd[n];
        outb[(rowG0 + n) * 512] = (ushort)f2bf(val);
        ++ptr;
    }
}

// -------- output projection on MFMA; A-operand from row-major hp1 --------
__global__ __launch_bounds__(256) void k_projm(const ushort* __restrict__ hp1,
                                               const ushort* __restrict__ pwf,
                                               const float* __restrict__ bias,
                                               float* __restrict__ out) {
    const int blk = blockIdx.x;          // 384 blocks, 32 rows each
    const int lane = threadIdx.x & 63;
    const int w = threadIdx.x >> 6;
    const int wrow = w >> 1, wcol = w & 1;
    const int lg = lane >> 4;
    const int ll = lane & 15;

    f32x4 acc[4];
#pragma unroll
    for (int nt = 0; nt < 4; ++nt) acc[nt] = (f32x4){0.f, 0.f, 0.f, 0.f};

    const int rt = blk * 2 + wrow;
    for (int kt = 0; kt < 16; ++kt) {
        bf16x8 afr = *(const bf16x8*)&hp1[(size_t)(rt * 16 + ll) * 512 + kt * 32 + lg * 8];
        bf16x8 bfr[4];
#pragma unroll
        for (int nt = 0; nt < 4; ++nt)
            bfr[nt] = *(const bf16x8*)&pwf[((kt * 8) + wcol * 4 + nt) * 512 + lane * 8];
#pragma unroll
        for (int nt = 0; nt < 4; ++nt)
            acc[nt] = __builtin_amdgcn_mfma_f32_16x16x32_bf16(afr, bfr[nt], acc[nt], 0, 0, 0);
    }

#pragma unroll
    for (int reg = 0; reg < 4; ++reg) {
        const int row = blk * 32 + wrow * 16 + lg * 4 + reg;
#pragma unroll
        for (int nt = 0; nt < 4; ++nt) {
            const int col = wcol * 64 + nt * 16 + ll;
            out[row * EMB_ + col] = acc[nt][reg] + bias[col];
        }
    }
}

extern "C" void kernel_launch(void* const* d_in, const int* in_sizes, int n_in,
                              void* d_out, int out_size, void* d_ws, size_t ws_size,
                              hipStream_t stream) {
    const float* x    = (const float*)d_in[0];
    const float* ip_w = (const float*)d_in[1];
    const float* ip_b = (const float*)d_in[2];
    const float* gw0  = (const float*)d_in[3];
    const float* ga0  = (const float*)d_in[4];
    const float* gw1  = (const float*)d_in[5];
    const float* ga1  = (const float*)d_in[6];
    const float* pw   = (const float*)d_in[7];
    const float* pb   = (const float*)d_in[8];
    float* out = (float*)d_out;

    ushort* h0r = (ushort*)d_ws;         // 786432 us (row-major h0, 12288x64)
    ushort* hp0 = h0r + 786432;          // 6291456 us (row-major, 12288x512)
    ushort* hp1 = hp0 + 6291456;         // 6291456 us
    ushort* W1f = hp1 + 6291456;         // 262144 us
    ushort* pwf = W1f + 262144;          // 65536 us
    ushort* W0f = pwf + 65536;           // 32768 us
    ushort* u1F = W0f + 32768;           // 65536 us
    ushort* u0F = u1F + 65536;           // 8192 us

    k_prep<<<704, 256, 0, stream>>>(x, ip_w, ip_b, gw1, pw, gw0, ga1, ga0,
                                    h0r, W1f, pwf, W0f, u1F, u0F);
    k_gat<2><<<256, 768, 0, stream>>>(h0r, W0f, u0F, hp0);
    k_gat<16><<<256, 768, 0, stream>>>(hp0, W1f, u1F, hp1);
    k_projm<<<(B_ * N_) / 32, 256, 0, stream>>>(hp1, pwf, pb, out);
}

// Round 12
// 138.896 us; speedup vs baseline: 2.0522x; 2.0522x over previous
//
#include <hip/hip_runtime.h>
#include <hip/hip_bf16.h>

// GAT encoder: B=16, N=768, IN=16, HID=64, HEADS=8, EMB=128, 2 GAT layers.
// Round 12: revert to round-10 structure (verified, 145.7us; round-11 sort-scan
// regressed 2x). One targeted change: truncation-packing for bf16 in k_gat hot
// paths (pk2: 2-3 ops/pair vs ~12 for RNE f2bf) -- phase-B af-gen, phase-A Wh
// epilogue, hbuf scale-store. Plus s_setprio(1) around MFMA clusters (waves are
// barrier-free inside the loops -> desynchronized, T5 precondition holds).
// k_prep / k_projm identical to round 10 (RNE kept on cold paths).
//
// ws: h0A us[786432] | hpA0 us[6291456] | hpA1 us[6291456] | W1f us[262144]
//     | pwf us[65536] | W0f us[32768] | u1F us[65536] | u0F us[8192]

#define B_ 16
#define N_ 768
#define IN_DIM_ 16
#define HID_ 64
#define EMB_ 128
#define NH_ 8
#define LOG2E_ 1.4426950408889634f

typedef __attribute__((ext_vector_type(4))) float f32x4;
typedef __attribute__((ext_vector_type(8))) short bf16x8;
typedef __attribute__((ext_vector_type(4))) short bf16x4;

typedef __attribute__((address_space(1))) const unsigned int gu32;
typedef __attribute__((address_space(3))) unsigned int lu32;

static __device__ __forceinline__ void gload_lds16(const void* g, void* l) {
    __builtin_amdgcn_global_load_lds((gu32*)g, (lu32*)l, 16, 0, 0);
}

static __device__ __forceinline__ short f2bf(float x) {   // RNE (cold paths)
    __hip_bfloat16 b = __float2bfloat16(x);
    return *reinterpret_cast<short*>(&b);
}
// truncation-pack two floats -> packed bf16 pair (lo = low short)
static __device__ __forceinline__ unsigned int pk2(float lo, float hi) {
    return (__float_as_uint(hi) & 0xFFFF0000u) | (__float_as_uint(lo) >> 16);
}
static __device__ __forceinline__ ushort tbf(float x) {   // truncate single
    return (ushort)(__float_as_uint(x) >> 16);
}

// ---- prep: h0A A-frags + W1f/pwf/W0f B-frags + u1F/u0F u-fragments ----
__global__ __launch_bounds__(256) void k_prep(const float* __restrict__ x,
                                              const float* __restrict__ ipw,
                                              const float* __restrict__ ipb,
                                              const float* __restrict__ w1,
                                              const float* __restrict__ pw,
                                              const float* __restrict__ w0,
                                              const float* __restrict__ a1g,
                                              const float* __restrict__ a0g,
                                              ushort* __restrict__ h0A,
                                              ushort* __restrict__ W1f,
                                              ushort* __restrict__ pwf,
                                              ushort* __restrict__ W0f,
                                              ushort* __restrict__ u1F,
                                              ushort* __restrict__ u0F) {
    const int bid = blockIdx.x;
    const int tid = threadIdx.x;
    if (bid < 384) {
        const int t = bid * 256 + tid;  // < 98304
        const int lane = t & 63;
        const int kt = (t >> 6) & 1;
        const int rtg = t >> 7;
        const int row = rtg * 16 + (lane & 15);
        const int k0 = kt * 32 + (lane >> 4) * 8;
        const float* xr = x + row * IN_DIM_;
        float xv[IN_DIM_];
#pragma unroll
        for (int f = 0; f < IN_DIM_; ++f) xv[f] = xr[f];
        bf16x8 v;
#pragma unroll
        for (int j = 0; j < 8; ++j) {
            float acc = ipb[k0 + j];
#pragma unroll
            for (int f = 0; f < IN_DIM_; ++f) acc = fmaf(xv[f], ipw[f * HID_ + k0 + j], acc);
            v[j] = f2bf(acc);
        }
        *(bf16x8*)&h0A[t * 8] = v;
        return;
    }
    if (bid < 560) {
        int t = (bid - 384) * 256 + tid;  // < 45056
        if (t < 32768) {
            int lane = t & 63, nt = (t >> 6) & 3, kt = (t >> 8) & 15, h = t >> 12;
            int k0 = kt * 32 + (lane >> 4) * 8;
            int col = nt * 16 + (lane & 15);
            const float* src = w1 + (h * 512 + k0) * 64 + col;
            bf16x8 v;
#pragma unroll
            for (int j = 0; j < 8; ++j) v[j] = f2bf(src[j * 64]);
            *(bf16x8*)&W1f[t * 8] = v;
        } else if (t < 40960) {
            int u = t - 32768;
            int lane = u & 63, nt = (u >> 6) & 7, kt = u >> 9;
            int k0 = kt * 32 + (lane >> 4) * 8;
            int col = nt * 16 + (lane & 15);
            const float* src = pw + k0 * 128 + col;
            bf16x8 v;
#pragma unroll
            for (int j = 0; j < 8; ++j) v[j] = f2bf(src[j * 128]);
            *(bf16x8*)&pwf[u * 8] = v;
        } else {
            int u = t - 40960;
            int lane = u & 63, nt = (u >> 6) & 3, kt = (u >> 8) & 1, h = u >> 9;
            int k0 = kt * 32 + (lane >> 4) * 8;
            int col = nt * 16 + (lane & 15);
            const float* src = w0 + (h * 64 + k0) * 64 + col;
            bf16x8 v;
#pragma unroll
            for (int j = 0; j < 8; ++j) v[j] = f2bf(src[j * 64]);
            *(bf16x8*)&W0f[u * 8] = v;
        }
        return;
    }
    // u-fragment blocks: one block per (layer,h,kt) -> zero + fill ll<2 lanes
    int ub = bid - 560;  // < 144
    const float* W;
    const float* A;
    ushort* dst;
    if (ub < 128) {
        int h = ub >> 4, kt = ub & 15;
        W = w1 + (h * 512 + kt * 32) * 64;
        A = a1g + h * 128;
        dst = u1F + (h * 16 + kt) * 512;
    } else {
        int v2 = ub - 128;
        int h = v2 >> 1, kt = v2 & 1;
        W = w0 + (h * 64 + kt * 32) * 64;
        A = a0g + h * 128;
        dst = u0F + (h * 2 + kt) * 512;
    }
    ((unsigned int*)dst)[tid] = 0u;   // zero 512 ushorts
    __syncthreads();
    const int sel = tid >> 7, kl = (tid >> 2) & 31, og4 = tid & 3;
    const float* Wr = W + kl * 64 + og4 * 16;
    const float* Ar = A + sel * 64 + og4 * 16;
    float r = 0.f;
#pragma unroll
    for (int q = 0; q < 4; ++q) {
        float4 wv = *(const float4*)&Wr[q * 4];
        float4 av = *(const float4*)&Ar[q * 4];
        r += wv.x * av.x + wv.y * av.y + wv.z * av.z + wv.w * av.w;
    }
    r += __shfl_xor(r, 1);
    r += __shfl_xor(r, 2);
    if (og4 == 0)
        dst[((kl >> 3) * 16 + sel) * 8 + (kl & 7)] = (ushort)f2bf(r * LOG2E_);
}

// ---- fused GAT layer: block (b,h,half), 12 waves -> Wh in LDS -> attention ----
template <int KT>
__global__ __launch_bounds__(768, 3) void k_gat(const ushort* __restrict__ Afrag,
                                                const ushort* __restrict__ Bfrag,
                                                const ushort* __restrict__ uF,
                                                ushort* __restrict__ hpA) {
    __shared__ __align__(16) char smem[98304];  // Whf frags; aliases W1f-stage / hbuf
    __shared__ __align__(16) float s1s[N_];
    __shared__ __align__(16) float s2s[N_];
    __shared__ __align__(16) float e2s[N_];
    __shared__ __align__(16) float f2s[N_];
    ushort* whf = (ushort*)smem;

    const int bid = blockIdx.x;
    const int b = bid & 15;           // same-b blocks share an XCD (bid%8 = b%8)
    const int hh = bid >> 4;
    const int h = hh >> 1;
    const int half = hh & 1;

    const int tid = threadIdx.x;
    const int lane = tid & 63;
    const int w = tid >> 6;       // 0..11
    const int lg = lane >> 4;
    const int ll = lane & 15;

    // ================= Phase A: Wh(768x64) + s1/s2 =================
    if constexpr (KT == 16) {
        const ushort* src = Bfrag + h * 16 * 2048;   // 64KB W1f[h] in 1KB wave-chunks
        for (int c = w; c < 64; c += 12)
            gload_lds16(src + c * 512 + lane * 8, (char*)smem + c * 1024);
        __syncthreads();
    }

    f32x4 acc[4][4];
    f32x4 accs[4];
#pragma unroll
    for (int i = 0; i < 4; ++i) {
        accs[i] = (f32x4){0.f, 0.f, 0.f, 0.f};
#pragma unroll
        for (int nt = 0; nt < 4; ++nt) acc[i][nt] = (f32x4){0.f, 0.f, 0.f, 0.f};
    }

    const int rt_base = b * 48 + w * 4;
    auto loadA4 = [&](bf16x8* dst, int kt) {
#pragma unroll
        for (int i = 0; i < 4; ++i)
            dst[i] = *(const bf16x8*)&Afrag[((rt_base + i) * KT + kt) * 512 + lane * 8];
    };
    auto loadB4 = [&](bf16x8* dst, int kt) {
        if constexpr (KT == 16) {
#pragma unroll
            for (int nt = 0; nt < 4; ++nt)
                dst[nt] = *(const bf16x8*)&whf[kt * 2048 + nt * 512 + lane * 8];
        } else {
#pragma unroll
            for (int nt = 0; nt < 4; ++nt)
                dst[nt] = *(const bf16x8*)&Bfrag[((h * 2 + kt) * 4 + nt) * 512 + lane * 8];
        }
    };
    auto stepA = [&](const bf16x8* afr, const bf16x8* bfr, bf16x8 ufr) {
        __builtin_amdgcn_s_setprio(1);
#pragma unroll
        for (int i = 0; i < 4; ++i) {
#pragma unroll
            for (int nt = 0; nt < 4; ++nt)
                acc[i][nt] = __builtin_amdgcn_mfma_f32_16x16x32_bf16(afr[i], bfr[nt], acc[i][nt], 0, 0, 0);
            accs[i] = __builtin_amdgcn_mfma_f32_16x16x32_bf16(afr[i], ufr, accs[i], 0, 0, 0);
        }
        __builtin_amdgcn_s_setprio(0);
    };

    {
        bf16x8 aA[4], aB[4];
        loadA4(aA, 0);
        for (int kt = 0; kt < KT; kt += 2) {
            loadA4(aB, kt + 1);                 // KT even: kt+1 < KT always
            bf16x8 bfr[4];
            loadB4(bfr, kt);
            bf16x8 ufr = *(const bf16x8*)&uF[(h * KT + kt) * 512 + lane * 8];
            stepA(aA, bfr, ufr);
            if (kt + 2 < KT) loadA4(aA, kt + 2);
            loadB4(bfr, kt + 1);
            ufr = *(const bf16x8*)&uF[(h * KT + kt + 1) * 512 + lane * 8];
            stepA(aB, bfr, ufr);
        }
    }
    if constexpr (KT == 16) __syncthreads();  // staged-B reads done before overwrite

    // Wh fragments -> LDS (j-packed b64, trunc-packed), s1/s2 -> LDS
#pragma unroll
    for (int i = 0; i < 4; ++i) {
        const int rt = w * 4 + i;
        const int lp = ((rt * 2 + (lg >> 1)) & 3) * 16 + ll;
        const int j0 = 4 * (lg & 1);
#pragma unroll
        for (int nt = 0; nt < 4; ++nt) {
            union { bf16x4 v; unsigned int u[2]; } pk;
            pk.u[0] = pk2(acc[i][nt][0], acc[i][nt][1]);
            pk.u[1] = pk2(acc[i][nt][2], acc[i][nt][3]);
            *(bf16x4*)&whf[(((rt >> 1) * 4 + nt) * 64 + lp) * 8 + j0] = pk.v;
        }
#pragma unroll
        for (int reg = 0; reg < 4; ++reg) {
            const int row = rt * 16 + lg * 4 + reg;
            if (ll == 0) s1s[row] = accs[i][reg];
            else if (ll == 1) s2s[row] = accs[i][reg];
        }
    }
    __syncthreads();

    // ---- factor arrays: e2 = 2^t2, f2 = 2^{0.2 t2}; per-thread e1/f1 ----
    for (int i = tid; i < N_; i += 768) {
        float t2 = s2s[i];
        e2s[i] = exp2f(t2);
        f2s[i] = exp2f(0.2f * t2);
    }
    const int qbase = half * 384 + w * 32;
    float e1v[2], f1v[2];
#pragma unroll
    for (int mt = 0; mt < 2; ++mt) {
        float t1 = s1s[qbase + mt * 16 + ll];
        e1v[mt] = exp2f(t1);
        f1v[mt] = exp2f(0.2f * t1);
    }
    __syncthreads();

    // ================= Phase B: attention (2 mt per wave) =================
    f32x4 pacc[2][4];
    f32x4 dacc[2];
#pragma unroll
    for (int mt = 0; mt < 2; ++mt) {
        dacc[mt] = (f32x4){0.f, 0.f, 0.f, 0.f};
#pragma unroll
        for (int nt = 0; nt < 4; ++nt) pacc[mt][nt] = (f32x4){0.f, 0.f, 0.f, 0.f};
    }
    bf16x8 onesB;
#pragma unroll
    for (int j = 0; j < 8; ++j) onesB[j] = (ll == 0) ? (short)0x3F80 : (short)0;

    auto loadP = [&](bf16x8* bq, float* ee, float* ff, int kt) {
#pragma unroll
        for (int nt = 0; nt < 4; ++nt)
            bq[nt] = *(const bf16x8*)&whf[kt * 2048 + nt * 512 + lane * 8];
        float4 t0 = *(const float4*)&e2s[kt * 32 + lg * 8];
        float4 t1 = *(const float4*)&e2s[kt * 32 + lg * 8 + 4];
        float4 t2 = *(const float4*)&f2s[kt * 32 + lg * 8];
        float4 t3 = *(const float4*)&f2s[kt * 32 + lg * 8 + 4];
        ee[0] = t0.x; ee[1] = t0.y; ee[2] = t0.z; ee[3] = t0.w;
        ee[4] = t1.x; ee[5] = t1.y; ee[6] = t1.z; ee[7] = t1.w;
        ff[0] = t2.x; ff[1] = t2.y; ff[2] = t2.z; ff[3] = t2.w;
        ff[4] = t3.x; ff[5] = t3.y; ff[6] = t3.z; ff[7] = t3.w;
    };
    auto stepB = [&](const bf16x8* bq, const float* ee, const float* ff) {
#pragma unroll
        for (int mt = 0; mt < 2; ++mt) {
            float p[8];
#pragma unroll
            for (int j = 0; j < 8; ++j)
                p[j] = fmaxf(e1v[mt] * ee[j], f1v[mt] * ff[j]);
            union { bf16x8 v; unsigned int u[4]; } af;
#pragma unroll
            for (int q = 0; q < 4; ++q) af.u[q] = pk2(p[2 * q], p[2 * q + 1]);
            __builtin_amdgcn_s_setprio(1);
            dacc[mt] = __builtin_amdgcn_mfma_f32_16x16x32_bf16(af.v, onesB, dacc[mt], 0, 0, 0);
#pragma unroll
            for (int nt = 0; nt < 4; ++nt)
                pacc[mt][nt] = __builtin_amdgcn_mfma_f32_16x16x32_bf16(af.v, bq[nt], pacc[mt][nt], 0, 0, 0);
            __builtin_amdgcn_s_setprio(0);
        }
    };

    {
        bf16x8 bqA[4], bqB[4];
        float eA[8], fA[8], eB[8], fB[8];
        loadP(bqA, eA, fA, 0);
        for (int kt = 0; kt < 24; kt += 2) {
            loadP(bqB, eB, fB, kt + 1);
            stepB(bqA, eA, fA);
            if (kt + 2 < 24) loadP(bqA, eA, fA, kt + 2);
            stepB(bqB, eB, fB);
        }
    }
    __syncthreads();   // all whf reads done; reuse smem as hbuf (384 rows x 128B)

    char* hb8 = smem;
#pragma unroll
    for (int mt = 0; mt < 2; ++mt) {
#pragma unroll
        for (int reg = 0; reg < 4; ++reg) {
            const int rl = w * 32 + mt * 16 + lg * 4 + reg;   // 0..383 local row
            const float dv = __shfl(dacc[mt][reg], lane & 0x30);  // rowsum at ll==0
            const float inv = 1.0f / dv;
            const int swz = (rl & 7) << 4;
#pragma unroll
            for (int nt = 0; nt < 4; ++nt) {
                int c = nt * 16 + ll;
                *(ushort*)(hb8 + rl * 128 + ((c * 2) ^ swz)) = tbf(pacc[mt][nt][reg] * inv);
            }
        }
    }
    __syncthreads();

    // fragment read + coalesced global store (verified epilogue, 2 rt-tiles/wave)
#pragma unroll
    for (int rt2 = 0; rt2 < 2; ++rt2) {
#pragma unroll
        for (int kc = 0; kc < 2; ++kc) {
            const int rtl = w * 2 + rt2;
            const int row = rtl * 16 + ll;
            bf16x8 v = *(const bf16x8*)(hb8 + row * 128 +
                                        ((kc * 64 + lg * 16) ^ ((row & 7) << 4)));
            const int rtg = b * 48 + half * 24 + rtl;
            *(bf16x8*)&hpA[((rtg * 16) + (h * 2 + kc)) * 512 + lane * 8] = v;
        }
    }
}

// -------- output projection on MFMA (verified round 5) --------
__global__ __launch_bounds__(256) void k_projm(const ushort* __restrict__ hpA,
                                               const ushort* __restrict__ pwf,
                                               const float* __restrict__ bias,
                                               float* __restrict__ out) {
    const int blk = blockIdx.x;          // 384 blocks, 32 rows each
    const int lane = threadIdx.x & 63;
    const int w = threadIdx.x >> 6;
    const int wrow = w >> 1, wcol = w & 1;
    const int lg = lane >> 4;
    const int ll = lane & 15;

    f32x4 acc[4];
#pragma unroll
    for (int nt = 0; nt < 4; ++nt) acc[nt] = (f32x4){0.f, 0.f, 0.f, 0.f};

    const int rt = blk * 2 + wrow;
    for (int kt = 0; kt < 16; ++kt) {
        bf16x8 afr = *(const bf16x8*)&hpA[((rt * 16) + kt) * 512 + lane * 8];
        bf16x8 bfr[4];
#pragma unroll
        for (int nt = 0; nt < 4; ++nt)
            bfr[nt] = *(const bf16x8*)&pwf[((kt * 8) + wcol * 4 + nt) * 512 + lane * 8];
#pragma unroll
        for (int nt = 0; nt < 4; ++nt)
            acc[nt] = __builtin_amdgcn_mfma_f32_16x16x32_bf16(afr, bfr[nt], acc[nt], 0, 0, 0);
    }

#pragma unroll
    for (int reg = 0; reg < 4; ++reg) {
        const int row = blk * 32 + wrow * 16 + lg * 4 + reg;
#pragma unroll
        for (int nt = 0; nt < 4; ++nt) {
            const int col = wcol * 64 + nt * 16 + ll;
            out[row * EMB_ + col] = acc[nt][reg] + bias[col];
        }
    }
}

extern "C" void kernel_launch(void* const* d_in, const int* in_sizes, int n_in,
                              void* d_out, int out_size, void* d_ws, size_t ws_size,
                              hipStream_t stream) {
    const float* x    = (const float*)d_in[0];
    const float* ip_w = (const float*)d_in[1];
    const float* ip_b = (const float*)d_in[2];
    const float* gw0  = (const float*)d_in[3];
    const float* ga0  = (const float*)d_in[4];
    const float* gw1  = (const float*)d_in[5];
    const float* ga1  = (const float*)d_in[6];
    const float* pw   = (const float*)d_in[7];
    const float* pb   = (const float*)d_in[8];
    float* out = (float*)d_out;

    ushort* h0A  = (ushort*)d_ws;        // 786432 us
    ushort* hpA0 = h0A + 786432;         // 6291456 us
    ushort* hpA1 = hpA0 + 6291456;       // 6291456 us
    ushort* W1f  = hpA1 + 6291456;       // 262144 us
    ushort* pwf  = W1f + 262144;         // 65536 us
    ushort* W0f  = pwf + 65536;          // 32768 us
    ushort* u1F  = W0f + 32768;          // 65536 us
    ushort* u0F  = u1F + 65536;          // 8192 us

    k_prep<<<704, 256, 0, stream>>>(x, ip_w, ip_b, gw1, pw, gw0, ga1, ga0,
                                    h0A, W1f, pwf, W0f, u1F, u0F);
    k_gat<2><<<256, 768, 0, stream>>>(h0A, W0f, u0F, hpA0);
    k_gat<16><<<256, 768, 0, stream>>>(hpA0, W1f, u1F, hpA1);
    k_projm<<<(B_ * N_) / 32, 256, 0, stream>>>(hpA1, pwf, pb, out);
}